// Round 1
// 447.044 us; speedup vs baseline: 1.0063x; 1.0063x over previous
//
#include <hip/hip_runtime.h>
#include <hip/hip_bf16.h>

// ---------------------------------------------------------------------------
// MoE (top-2 of 8 experts), B=4 T=2048 C=1024 H=2048 E=8. FP32 in/out;
// internal GEMMs in bf16 MFMA. Round 7: both GEMM K-loops restructured into a
// counted-vmcnt software pipeline (T3+T4): K-tile split into two kh=32 phases,
// LDS double-buffered [mat][buf][kh][128][32], chunk-groups issued 2 phases
// ahead, s_waitcnt vmcnt(8) (never 0 mid-loop), setprio(1) around MFMA (T5).
// Tile geometry, wave mapping, epilogue, grids, prep/scatter/combine and the
// launcher are unchanged from round 6.
// ---------------------------------------------------------------------------

#define NTOK 8192
#define CD   1024
#define HD   2048
#define NE   8
#define NSLOT 16384   // NTOK * top_k
#define MTILES 20     // supports up to 2560 tokens per expert (mean 2048, 12 sigma)
#define BK   64
#define NT1  (CD / BK)   // 16 K-tiles in gemm1
#define NT2  (HD / BK)   // 32 K-tiles in gemm2
#define PACK_BLOCKS 2048   // 64 x 32 tile grid per weight tensor

typedef short  short4_t  __attribute__((ext_vector_type(4)));
typedef short  short8_t  __attribute__((ext_vector_type(8)));
typedef __bf16 bf16x8_t  __attribute__((ext_vector_type(8)));
typedef float  f32x4_t   __attribute__((ext_vector_type(4)));

// MFMA builtin arg-type shim: satisfies either V8s or V8bf16 signatures.
struct FragArg {
  short8_t v;
  __device__ operator short8_t() const { return v; }
  __device__ operator bf16x8_t() const { return __builtin_bit_cast(bf16x8_t, v); }
};

static __device__ __forceinline__ float b2f(unsigned short u) {
  union { float f; unsigned int i; } w; w.i = ((unsigned int)u) << 16; return w.f;
}
static __device__ __forceinline__ unsigned short f2b(float f) {
  unsigned int u = __float_as_uint(f);
  u += 0x7fffu + ((u >> 16) & 1u);           // round-to-nearest-even
  return (unsigned short)(u >> 16);
}
static __device__ __forceinline__ void gl2lds16(const void* g, void* l) {
  __builtin_amdgcn_global_load_lds((__attribute__((address_space(1))) void*)g,
                                   (__attribute__((address_space(3))) void*)l,
                                   16, 0, 0);
}

// ---- weight pack tile: fp32 (D0,D1,8) -> bf16 (8,D1,D0), one 32x32 tile ----
// smem must hold NE*32*40 unsigned shorts (20480 B).
static __device__ __forceinline__ void pack_tile(
    const float* __restrict__ in, unsigned short* __restrict__ out,
    int D0, int D1, int b0, int b1, unsigned short* smem, int t)
{
  int d1i = t & 31, d0q = t >> 5;
  #pragma unroll
  for (int r = 0; r < 4; ++r) {
    int d0i = d0q * 4 + r;
    const float* src = in + ((size_t)(b0 + d0i) * D1 + (b1 + d1i)) * NE;
    float4 v0 = *(const float4*)src;
    float4 v1 = *(const float4*)(src + 4);
    unsigned short* dst0 = &smem[d1i * 40 + d0i];
    dst0[0 * 32 * 40] = f2b(v0.x);
    dst0[1 * 32 * 40] = f2b(v0.y);
    dst0[2 * 32 * 40] = f2b(v0.z);
    dst0[3 * 32 * 40] = f2b(v0.w);
    dst0[4 * 32 * 40] = f2b(v1.x);
    dst0[5 * 32 * 40] = f2b(v1.y);
    dst0[6 * 32 * 40] = f2b(v1.z);
    dst0[7 * 32 * 40] = f2b(v1.w);
  }
  __syncthreads();
  int dchunk = t & 3, d1w = (t >> 2) & 31, ehalf = t >> 7;
  #pragma unroll
  for (int p = 0; p < 4; ++p) {
    int e = ehalf + 2 * p;
    short8_t v = *(const short8_t*)&smem[e * 32 * 40 + d1w * 40 + dchunk * 8];
    *(short8_t*)(out + ((size_t)e * D1 + (b1 + d1w)) * D0 + b0 + dchunk * 8) = v;
  }
}

// ---- prep: blocks [0,2048) = gate(+x->bf16, +histogram);
//      blocks [2048,4096) = pack wfc (C,H,E) -> wfcp (E,H,C) ----------------
#define GATE_BLOCKS (NTOK / 4)
__global__ __launch_bounds__(256) void prep_kernel(
    const float* __restrict__ x, const float* __restrict__ wg,
    const float* __restrict__ wfc,
    unsigned short* __restrict__ xb, unsigned short* __restrict__ wfcp,
    int* __restrict__ tok_e, float* __restrict__ tok_v,
    int* __restrict__ g_counts)
{
  __shared__ __align__(16) unsigned short lds[NE * 32 * 40];  // pack role
  __shared__ int hist[NE];                                    // gate role
  int t = threadIdx.x;

  if (blockIdx.x < GATE_BLOCKS) {
    // ---------------- gate role: one wave per token ----------------
    if (t < NE) hist[t] = 0;
    __syncthreads();
    int wv = t >> 6, lane = t & 63;
    int tk = blockIdx.x * 4 + wv;
    const float* xr = x + (size_t)tk * CD;
    unsigned short* xbr = xb + (size_t)tk * CD;
    float acc[NE] = {0, 0, 0, 0, 0, 0, 0, 0};
    #pragma unroll
    for (int jj = 0; jj < 4; ++jj) {
      int c0 = (lane + 64 * jj) * 4;
      float4 xv = *(const float4*)(xr + c0);
      short4_t ob;                             // fused fp32->bf16 of x
      ob[0] = (short)f2b(xv.x); ob[1] = (short)f2b(xv.y);
      ob[2] = (short)f2b(xv.z); ob[3] = (short)f2b(xv.w);
      *(short4_t*)(xbr + c0) = ob;
      #pragma unroll
      for (int j = 0; j < 4; ++j) {
        float xf = (j == 0) ? xv.x : (j == 1) ? xv.y : (j == 2) ? xv.z : xv.w;
        const float* wr = wg + (size_t)(c0 + j) * NE;
        float4 w0 = *(const float4*)wr;
        float4 w1 = *(const float4*)(wr + 4);
        acc[0] += xf * w0.x; acc[1] += xf * w0.y;
        acc[2] += xf * w0.z; acc[3] += xf * w0.w;
        acc[4] += xf * w1.x; acc[5] += xf * w1.y;
        acc[6] += xf * w1.z; acc[7] += xf * w1.w;
      }
    }
    #pragma unroll
    for (int off = 32; off >= 1; off >>= 1)
      #pragma unroll
      for (int e = 0; e < NE; ++e) acc[e] += __shfl_down(acc[e], off, 64);
    if (lane == 0) {
      float v1 = -3.0e38f, v2 = -3.0e38f; int i1 = 0, i2 = 1;
      #pragma unroll
      for (int e = 0; e < NE; ++e) {          // strict '>' => ties keep lower idx
        float g = acc[e];
        if (g > v1) { v2 = v1; i2 = i1; v1 = g; i1 = e; }
        else if (g > v2) { v2 = g; i2 = e; }
      }
      tok_e[tk * 2] = i1; tok_e[tk * 2 + 1] = i2;
      tok_v[tk * 2] = v1; tok_v[tk * 2 + 1] = v2;
      atomicAdd(&hist[i1], 1); atomicAdd(&hist[i2], 1);
    }
    __syncthreads();
    if (t < NE && hist[t] > 0) atomicAdd(&g_counts[t], hist[t]);
  } else {
    // ------------- pack wfc: D0=CD (by, 32 tiles), D1=HD (bx, 64) ----------
    int pid = blockIdx.x - GATE_BLOCKS;
    int bx = pid & 63, by = pid >> 6;
    pack_tile(wfc, wfcp, CD, HD, by * 32, bx * 32, lds, t);
  }
}

// ------ scatter: 64 blocks, wave-aggregated atomics on g_cursor ------------
__global__ __launch_bounds__(256) void scatter_kernel(
    const int* __restrict__ tok_e, const float* __restrict__ tok_v,
    const int* __restrict__ g_counts, int* __restrict__ g_cursor,
    int* __restrict__ g_base,
    int* __restrict__ bucket_tok, float* __restrict__ bucket_v,
    int* __restrict__ slot_of)
{
  int gid = blockIdx.x * 256 + threadIdx.x;   // 16384 threads, 1 slot each
  int lane = threadIdx.x & 63;
  int base[NE];
  { int o = 0;
    #pragma unroll
    for (int e = 0; e < NE; ++e) { base[e] = o; o += g_counts[e]; } }
  int e = tok_e[gid];
  unsigned long long lanebit = 1ull << lane;
  int pos = 0;
  #pragma unroll
  for (int ee = 0; ee < NE; ++ee) {
    unsigned long long m = __ballot(e == ee);
    if (e == ee) {
      int leader = __ffsll((long long)m) - 1;
      int cnt = __popcll(m);
      int start = 0;
      if (lane == leader) start = atomicAdd(&g_cursor[ee], cnt);
      start = __shfl(start, leader, 64);
      pos = start + __popcll(m & (lanebit - 1));
    }
  }
  int sl = base[e] + pos;
  bucket_tok[sl] = gid >> 1;
  bucket_v[sl]   = tok_v[gid];
  slot_of[gid]   = sl;
  if (gid < NE) g_base[gid] = base[gid];
}

// ------------------- GEMM1 (+ hidden wpj pack role) ------------------------
// blocks [0,2048): pack wpj (H,C,E) -> wpjp (E,C,H)  [consumed only by gemm2]
// blocks [2048,...): h = v * silu(x_rows @ WfcT); e=(id-2048)&7 -> XCD-pinned.
// K-loop: counted-vmcnt pipeline. LDS [mat][buf][kh][128][32], chunk-group =
// 4 gl2lds (A rows 0-63, A 64-127, B 0-63, B 64-127 of one kh half). Issue
// schedule: phase(kh=0) of tile t stages (t+1,kh=1); phase(kh=1) stages
// (t+2,kh=0). Each group's guarding wait is vmcnt(8) two phases later.
__global__ __launch_bounds__(256, 2) void gemm1_kernel(
    const unsigned short* __restrict__ xb, const unsigned short* __restrict__ wfcp,
    const float* __restrict__ wpj, unsigned short* __restrict__ wpjp,
    const int* __restrict__ g_counts, const int* __restrict__ g_base,
    const int* __restrict__ bucket_tok, const float* __restrict__ bucket_v,
    unsigned short* __restrict__ hbuf)
{
  // [mat A/B][buf][kh][row][32] bf16 = 64 KiB; pack role reuses first 20 KiB.
  __shared__ __align__(16) unsigned short smem[2][2][2][128][32];
  __shared__ int   s_tok[128];
  __shared__ float s_v[128];
  int t = threadIdx.x;

  if (blockIdx.x < PACK_BLOCKS) {
    // ------------- pack wpj: D0=HD (bx, 64 tiles), D1=CD (by, 32) ----------
    int pid = blockIdx.x;
    int bx = pid & 63, by = pid >> 6;
    pack_tile(wpj, wpjp, HD, CD, bx * 32, by * 32, &smem[0][0][0][0][0], t);
    return;
  }

  int id = blockIdx.x - PACK_BLOCKS;
  int e = id & 7;
  int r = id >> 3;
  int nt = r & 15;                 // HD/128 = 16 n-tiles, fastest
  int mt = r >> 4;                 // [0, MTILES)

  int cnt = g_counts[e];
  int m0 = mt * 128;
  if (m0 >= cnt) return;
  int base = g_base[e];
  int n0 = nt * 128;

  if (t < 128) {
    int ok = (m0 + t) < cnt;
    s_tok[t] = ok ? bucket_tok[base + m0 + t] : 0;
    s_v[t]   = ok ? bucket_v[base + m0 + t] : 0.0f;
  }
  __syncthreads();   // also drains all prior vmem -> clean vmcnt slate

  int lane = t & 63, wv = t >> 6;
  // staging map: thread -> (row srow / srow+64, 16B piece spc); source column
  // pre-swizzled so linear gl2lds dst yields the swizzled LDS layout.
  int srow = t >> 2;               // 0..63
  int spc  = t & 3;
  int sw   = (spc ^ (srow & 3)) * 8;      // (srow+64)&3 == srow&3
  const unsigned short* aS0 = xb + (size_t)s_tok[srow] * CD + sw;
  const unsigned short* aS1 = xb + (size_t)s_tok[srow + 64] * CD + sw;
  const unsigned short* bS0 = wfcp + ((size_t)e * HD + n0 + srow) * CD + sw;
  const unsigned short* bS1 = wfcp + ((size_t)e * HD + n0 + srow + 64) * CD + sw;

  #define STG1(tt, kh) do {                                              \
    int _ko = (tt) * BK + (kh) * 32;                                     \
    int _b  = (tt) & 1;                                                  \
    gl2lds16(aS0 + _ko, &smem[0][_b][kh][wv * 16][0]);                   \
    gl2lds16(aS1 + _ko, &smem[0][_b][kh][64 + wv * 16][0]);              \
    gl2lds16(bS0 + _ko, &smem[1][_b][kh][wv * 16][0]);                   \
    gl2lds16(bS1 + _ko, &smem[1][_b][kh][64 + wv * 16][0]);              \
  } while (0)

  int wm = (wv & 1) * 64, wn = (wv >> 1) * 64;
  int ml = lane & 15, kq = lane >> 4;
  int sw8 = (kq ^ (ml & 3)) * 8;   // frag-read swizzle (row&3 == ml&3)

  f32x4_t acc[4][4];
  #pragma unroll
  for (int i = 0; i < 4; ++i)
    #pragma unroll
    for (int j = 0; j < 4; ++j) acc[i][j] = (f32x4_t){0.f, 0.f, 0.f, 0.f};

  // prologue: tile0 (both halves) + tile1 kh0 = 3 groups, 12 loads.
  STG1(0, 0); STG1(0, 1); STG1(1, 0);
  asm volatile("s_waitcnt vmcnt(8)" ::: "memory");   // group(0,0) complete
  __builtin_amdgcn_s_barrier();
  asm volatile("" ::: "memory");

  #pragma unroll 1
  for (int tt = 0; tt < NT1; ++tt) {
    int buf = tt & 1;
    short8_t af[4], bfr[4];
    // ---------------- phase kh = 0 ----------------
    #pragma unroll
    for (int i = 0; i < 4; ++i) {
      af[i]  = *(const short8_t*)&smem[0][buf][0][wm + i * 16 + ml][sw8];
      bfr[i] = *(const short8_t*)&smem[1][buf][0][wn + i * 16 + ml][sw8];
    }
    if (tt + 1 < NT1) STG1(tt + 1, 1);
    __builtin_amdgcn_s_barrier();
    __builtin_amdgcn_s_setprio(1);
    #pragma unroll
    for (int i = 0; i < 4; ++i)
      #pragma unroll
      for (int j = 0; j < 4; ++j)
        acc[i][j] = __builtin_amdgcn_mfma_f32_16x16x32_bf16(
            FragArg{af[i]}, FragArg{bfr[j]}, acc[i][j], 0, 0, 0);
    __builtin_amdgcn_s_setprio(0);
    if (tt < NT1 - 1) asm volatile("s_waitcnt vmcnt(8)" ::: "memory");
    else              asm volatile("s_waitcnt vmcnt(0)" ::: "memory");
    __builtin_amdgcn_s_barrier();
    asm volatile("" ::: "memory");
    // ---------------- phase kh = 1 ----------------
    #pragma unroll
    for (int i = 0; i < 4; ++i) {
      af[i]  = *(const short8_t*)&smem[0][buf][1][wm + i * 16 + ml][sw8];
      bfr[i] = *(const short8_t*)&smem[1][buf][1][wn + i * 16 + ml][sw8];
    }
    if (tt + 2 < NT1) STG1(tt + 2, 0);
    __builtin_amdgcn_s_barrier();
    __builtin_amdgcn_s_setprio(1);
    #pragma unroll
    for (int i = 0; i < 4; ++i)
      #pragma unroll
      for (int j = 0; j < 4; ++j)
        acc[i][j] = __builtin_amdgcn_mfma_f32_16x16x32_bf16(
            FragArg{af[i]}, FragArg{bfr[j]}, acc[i][j], 0, 0, 0);
    __builtin_amdgcn_s_setprio(0);
    if (tt + 2 < NT1)      asm volatile("s_waitcnt vmcnt(8)" ::: "memory");
    else if (tt + 1 < NT1) asm volatile("s_waitcnt vmcnt(4)" ::: "memory");
    __builtin_amdgcn_s_barrier();
    asm volatile("" ::: "memory");
  }
  #undef STG1

  #pragma unroll
  for (int i = 0; i < 4; ++i) {
    int rb = wm + i * 16 + kq * 4;
    #pragma unroll
    for (int r2 = 0; r2 < 4; ++r2) {
      int row = rb + r2;
      if (m0 + row < cnt) {
        float v = s_v[row];
        size_t ro = (size_t)(base + m0 + row) * HD + n0;
        #pragma unroll
        for (int j = 0; j < 4; ++j) {
          float z = acc[i][j][r2];
          float val = v * (z / (1.0f + __expf(-z)));   // gate_w * silu(z)
          hbuf[ro + wn + j * 16 + ml] = f2b(val);
        }
      }
    }
  }
}

// ------------------- GEMM2: o_slot = h_rows @ WprojT -----------------------
// Same counted-vmcnt pipeline as gemm1; NT2 = 32 K-tiles.
__global__ __launch_bounds__(256, 2) void gemm2_kernel(
    const unsigned short* __restrict__ hbuf, const unsigned short* __restrict__ wpjp,
    const int* __restrict__ g_counts, const int* __restrict__ g_base,
    unsigned short* __restrict__ oslot)
{
  __shared__ __align__(16) unsigned short smem[2][2][2][128][32];

  int id = blockIdx.x;
  int e = id & 7;
  int r = id >> 3;
  int nt = r & 7;                  // CD/128 = 8 n-tiles, fastest
  int mt = r >> 3;                 // [0, MTILES)

  int cnt = g_counts[e];
  int m0 = mt * 128;
  if (m0 >= cnt) return;
  int base = g_base[e];
  int n0 = nt * 128;

  int t = threadIdx.x;
  int lane = t & 63, wv = t >> 6;
  int srow = t >> 2;               // 0..63
  int spc  = t & 3;
  int sw   = (spc ^ (srow & 3)) * 8;
  // Padded rows over-read past hbuf into oslot region (inside d_ws); their
  // stores are guarded below; garbage only lands in discarded output rows.
  const unsigned short* aS0 = hbuf + ((size_t)(base + m0 + srow)) * HD + sw;
  const unsigned short* aS1 = hbuf + ((size_t)(base + m0 + srow + 64)) * HD + sw;
  const unsigned short* bS0 = wpjp + ((size_t)e * CD + n0 + srow) * HD + sw;
  const unsigned short* bS1 = wpjp + ((size_t)e * CD + n0 + srow + 64) * HD + sw;

  #define STG2(tt, kh) do {                                              \
    int _ko = (tt) * BK + (kh) * 32;                                     \
    int _b  = (tt) & 1;                                                  \
    gl2lds16(aS0 + _ko, &smem[0][_b][kh][wv * 16][0]);                   \
    gl2lds16(aS1 + _ko, &smem[0][_b][kh][64 + wv * 16][0]);              \
    gl2lds16(bS0 + _ko, &smem[1][_b][kh][wv * 16][0]);                   \
    gl2lds16(bS1 + _ko, &smem[1][_b][kh][64 + wv * 16][0]);              \
  } while (0)

  int wm = (wv & 1) * 64, wn = (wv >> 1) * 64;
  int ml = lane & 15, kq = lane >> 4;
  int sw8 = (kq ^ (ml & 3)) * 8;

  f32x4_t acc[4][4];
  #pragma unroll
  for (int i = 0; i < 4; ++i)
    #pragma unroll
    for (int j = 0; j < 4; ++j) acc[i][j] = (f32x4_t){0.f, 0.f, 0.f, 0.f};

  // drain any prior vector-memory ops (uniform loads etc.) for clean counts
  asm volatile("s_waitcnt vmcnt(0)" ::: "memory");
  STG2(0, 0); STG2(0, 1); STG2(1, 0);
  asm volatile("s_waitcnt vmcnt(8)" ::: "memory");
  __builtin_amdgcn_s_barrier();
  asm volatile("" ::: "memory");

  #pragma unroll 1
  for (int tt = 0; tt < NT2; ++tt) {
    int buf = tt & 1;
    short8_t af[4], bfr[4];
    // ---------------- phase kh = 0 ----------------
    #pragma unroll
    for (int i = 0; i < 4; ++i) {
      af[i]  = *(const short8_t*)&smem[0][buf][0][wm + i * 16 + ml][sw8];
      bfr[i] = *(const short8_t*)&smem[1][buf][0][wn + i * 16 + ml][sw8];
    }
    if (tt + 1 < NT2) STG2(tt + 1, 1);
    __builtin_amdgcn_s_barrier();
    __builtin_amdgcn_s_setprio(1);
    #pragma unroll
    for (int i = 0; i < 4; ++i)
      #pragma unroll
      for (int j = 0; j < 4; ++j)
        acc[i][j] = __builtin_amdgcn_mfma_f32_16x16x32_bf16(
            FragArg{af[i]}, FragArg{bfr[j]}, acc[i][j], 0, 0, 0);
    __builtin_amdgcn_s_setprio(0);
    if (tt < NT2 - 1) asm volatile("s_waitcnt vmcnt(8)" ::: "memory");
    else              asm volatile("s_waitcnt vmcnt(0)" ::: "memory");
    __builtin_amdgcn_s_barrier();
    asm volatile("" ::: "memory");
    // ---------------- phase kh = 1 ----------------
    #pragma unroll
    for (int i = 0; i < 4; ++i) {
      af[i]  = *(const short8_t*)&smem[0][buf][1][wm + i * 16 + ml][sw8];
      bfr[i] = *(const short8_t*)&smem[1][buf][1][wn + i * 16 + ml][sw8];
    }
    if (tt + 2 < NT2) STG2(tt + 2, 0);
    __builtin_amdgcn_s_barrier();
    __builtin_amdgcn_s_setprio(1);
    #pragma unroll
    for (int i = 0; i < 4; ++i)
      #pragma unroll
      for (int j = 0; j < 4; ++j)
        acc[i][j] = __builtin_amdgcn_mfma_f32_16x16x32_bf16(
            FragArg{af[i]}, FragArg{bfr[j]}, acc[i][j], 0, 0, 0);
    __builtin_amdgcn_s_setprio(0);
    if (tt + 2 < NT2)      asm volatile("s_waitcnt vmcnt(8)" ::: "memory");
    else if (tt + 1 < NT2) asm volatile("s_waitcnt vmcnt(4)" ::: "memory");
    __builtin_amdgcn_s_barrier();
    asm volatile("" ::: "memory");
  }
  #undef STG2

  #pragma unroll
  for (int i = 0; i < 4; ++i) {
    int rb = wm + i * 16 + kq * 4;
    #pragma unroll
    for (int r2 = 0; r2 < 4; ++r2) {
      int row = rb + r2;
      if (m0 + row < cnt) {
        size_t ro = (size_t)(base + m0 + row) * CD + n0;
        #pragma unroll
        for (int j = 0; j < 4; ++j)
          oslot[ro + wn + j * 16 + ml] = f2b(acc[i][j][r2]);
      }
    }
  }
}

// ----------- combine: out[t] = fp32(oslot[s0]) + fp32(oslot[s1]) -----------
__global__ __launch_bounds__(256) void combine_kernel(
    const unsigned short* __restrict__ oslot, const int* __restrict__ slot_of,
    float* __restrict__ out)
{
  int gid = blockIdx.x * 256 + threadIdx.x;
  int tk = gid >> 7;               // 128 chunks of 8 per token
  int ch = (gid & 127) * 8;
  int s0 = slot_of[tk * 2], s1 = slot_of[tk * 2 + 1];
  short8_t a = *(const short8_t*)(oslot + (size_t)s0 * CD + ch);
  short8_t b = *(const short8_t*)(oslot + (size_t)s1 * CD + ch);
  float* op = out + (size_t)tk * CD + ch;
  float4 o0, o1;
  o0.x = b2f((unsigned short)a[0]) + b2f((unsigned short)b[0]);
  o0.y = b2f((unsigned short)a[1]) + b2f((unsigned short)b[1]);
  o0.z = b2f((unsigned short)a[2]) + b2f((unsigned short)b[2]);
  o0.w = b2f((unsigned short)a[3]) + b2f((unsigned short)b[3]);
  o1.x = b2f((unsigned short)a[4]) + b2f((unsigned short)b[4]);
  o1.y = b2f((unsigned short)a[5]) + b2f((unsigned short)b[5]);
  o1.z = b2f((unsigned short)a[6]) + b2f((unsigned short)b[6]);
  o1.w = b2f((unsigned short)a[7]) + b2f((unsigned short)b[7]);
  *(float4*)op = o0;
  *(float4*)(op + 4) = o1;
}

// ---------------------------------------------------------------------------
extern "C" void kernel_launch(void* const* d_in, const int* in_sizes, int n_in,
                              void* d_out, int out_size, void* d_ws, size_t ws_size,
                              hipStream_t stream)
{
  const float* x   = (const float*)d_in[0];
  const float* wg  = (const float*)d_in[1];
  const float* wfc = (const float*)d_in[2];
  const float* wpj = (const float*)d_in[3];
  float* out = (float*)d_out;

  // workspace carve-up (~185 MB). hbuf precedes oslot so padded-tile A
  // over-reads in gemm2 stay inside d_ws.
  char* w = (char*)d_ws;
  unsigned short* wfcp  = (unsigned short*)w; w += (size_t)NE * HD * CD * 2;  // 33.5 MB
  unsigned short* wpjp  = (unsigned short*)w; w += (size_t)NE * CD * HD * 2;  // 33.5 MB
  unsigned short* xb    = (unsigned short*)w; w += (size_t)NTOK * CD * 2;     // 16.8 MB
  unsigned short* hbuf  = (unsigned short*)w; w += (size_t)NSLOT * HD * 2;    // 67.1 MB
  unsigned short* oslot = (unsigned short*)w; w += (size_t)NSLOT * CD * 2;    // 33.5 MB
  int*   tok_e      = (int*)w;   w += NSLOT * 4;
  float* tok_v      = (float*)w; w += NSLOT * 4;
  int*   slot_of    = (int*)w;   w += NSLOT * 4;
  int*   bucket_tok = (int*)w;   w += NSLOT * 4;
  float* bucket_v   = (float*)w; w += NSLOT * 4;
  int*   g_counts   = (int*)w;   w += NE * 4;   // contiguous with g_cursor:
  int*   g_cursor   = (int*)w;   w += NE * 4;   // one 64B memset covers both
  int*   g_base     = (int*)w;   w += 256;

  hipMemsetAsync(g_counts, 0, 2 * NE * sizeof(int), stream);
  prep_kernel<<<GATE_BLOCKS + PACK_BLOCKS, 256, 0, stream>>>(
      x, wg, wfc, xb, wfcp, tok_e, tok_v, g_counts);
  scatter_kernel<<<NSLOT / 256, 256, 0, stream>>>(
      tok_e, tok_v, g_counts, g_cursor, g_base, bucket_tok, bucket_v, slot_of);
  gemm1_kernel<<<PACK_BLOCKS + (HD / 128) * MTILES * NE, 256, 0, stream>>>(
      xb, wfcp, wpj, wpjp, g_counts, g_base, bucket_tok, bucket_v, hbuf);
  gemm2_kernel<<<(CD / 128) * MTILES * NE, 256, 0, stream>>>(
      hbuf, wpjp, g_counts, g_base, oslot);
  combine_kernel<<<(NTOK * CD / 8) / 256, 256, 0, stream>>>(oslot, slot_of, out);
}